// Round 16
// baseline (233.357 us; speedup 1.0000x reference)
//
#include <hip/hip_runtime.h>
#include <hip/hip_fp16.h>
#include <hip/hip_cooperative_groups.h>
#include <math.h>

#define DT 0.005f
#define NTHREADS 256
#define NBLOCKS 2048
#define NBUCKET 32
#define ELEMS_PER_BLOCK 1024
#define ROUNDS 4

namespace cg = cooperative_groups;

typedef float    fvec4 __attribute__((ext_vector_type(4)));
typedef float    fvec2 __attribute__((ext_vector_type(2)));
typedef unsigned uvec4 __attribute__((ext_vector_type(4)));
// 4-byte-aligned 16B vector (gfx9 allows dword-aligned dwordx4; proven r15)
typedef float    fvec4u __attribute__((ext_vector_type(4), aligned(4)));

__device__ __forceinline__ fvec4 ntload4f(const float* p) {
    return __builtin_nontemporal_load(reinterpret_cast<const fvec4*>(p));
}
__device__ __forceinline__ float ntloadf(const float* p) {
    return __builtin_nontemporal_load(p);
}
__device__ __forceinline__ int ntloadi(const int* p) {
    return __builtin_nontemporal_load(p);
}
__device__ __forceinline__ unsigned long long ntload8(const unsigned long long* p) {
    return __builtin_nontemporal_load(p);
}

__device__ __forceinline__ unsigned short f2h(float f) {
    return __half_as_ushort(__float2half(f));
}
__device__ __forceinline__ float h2f(unsigned short u) {
    return __half2float(__ushort_as_half(u));
}

__device__ __forceinline__ void stream_compute(
    const float* __restrict__ quat, const float* __restrict__ tpos,
    const float* __restrict__ bias, const float* __restrict__ batchX,
    int i, int SF, int last_off,
    float gx, float gy, float gz, float half_dt2,
    float& cx, float& cy, float& cz)
{
    fvec4 q = ntload4f(quat + (size_t)i * 4);
    const float* tp = tpos + (size_t)i * 3;
    float tpx = ntloadf(tp + 0), tpy = ntloadf(tp + 1), tpz = ntloadf(tp + 2);
    const float* bp = bias + (size_t)i * 3;
    float bx = ntloadf(bp + 0), by = ntloadf(bp + 1), bz = ntloadf(bp + 2);
    // single 16B load (4B-aligned) covering the 12B accel sample
    const float* xb = batchX + (size_t)i * SF + last_off;
    fvec4u a = *reinterpret_cast<const fvec4u*>(xb);
    float ax = a.x - bx;
    float ay = a.y - by;
    float az = a.z - bz;

    float t0 = -(q.y * ax + q.z * ay + q.w * az);
    float t1 =   q.x * ax + q.z * az - q.w * ay;
    float t2 =   q.x * ay - q.y * az + q.w * ax;
    float t3 =   q.x * az + q.y * ay - q.z * ax;
    float rx = -t0 * q.y + t1 * q.x - t2 * q.w + t3 * q.z;
    float ry = -t0 * q.z + t1 * q.w + t2 * q.x - t3 * q.y;
    float rz = -t0 * q.w - t1 * q.z + t2 * q.y + t3 * q.x;

    cx = half_dt2 * (gx + rx) - tpx;
    cy = half_dt2 * (gy + ry) - tpy;
    cz = half_dt2 * (gz + rz) - tpz;
}

__device__ __forceinline__ float huber3(float dx, float dy, float dz) {
    float adx = fabsf(dx), ady = fabsf(dy), adz = fabsf(dz);
    float h = (adx < 1.f) ? 0.5f * dx * dx : adx - 0.5f;
    h += (ady < 1.f) ? 0.5f * dy * dy : ady - 0.5f;
    h += (adz < 1.f) ? 0.5f * dz * dz : adz - 0.5f;
    return h;
}

// ---------------- K1: stream + deterministic 32-bucket multisplit, 8B packed ----------------
__global__ __launch_bounds__(NTHREADS) void k1_bin(
    const float* __restrict__ quat,
    const float* __restrict__ tpos,
    const float* __restrict__ bias,
    const float* __restrict__ batchX,
    const float* __restrict__ grav,
    const int*   __restrict__ indices,
    const int*   __restrict__ seq_len_p,
    int SF, int shift,
    unsigned long long* __restrict__ pairs8,
    int*   __restrict__ dirs)
{
    const int S = *seq_len_p;
    const int F = SF / S;
    const int last_off = (S - 1) * F;
    const float gx = grav[0], gy = grav[1], gz = grav[2];
    const float half_dt2 = 0.5f * DT * DT;

    __shared__ int   cnt[ROUNDS][4][NBUCKET];
    __shared__ int   offarr[ROUNDS][4][NBUCKET];
    __shared__ int   bstart[NBUCKET];
    __shared__ unsigned long long stage[ELEMS_PER_BLOCK];

    const int tid  = threadIdx.x;
    const int wave = tid >> 6;
    const int lane = tid & 63;
    const unsigned long long ltmask = (1ull << lane) - 1ull;

    for (int k = tid; k < ROUNDS * 4 * NBUCKET; k += NTHREADS)
        ((int*)cnt)[k] = 0;
    __syncthreads();

    const int base = blockIdx.x * ELEMS_PER_BLOCK;

    int   idxv[ROUNDS], bckt[ROUNDS], rnk[ROUNDS];
    float cxv[ROUNDS], cyv[ROUNDS], czv[ROUNDS];

    #pragma unroll
    for (int r = 0; r < ROUNDS; ++r) {
        const int i = base + r * NTHREADS + tid;
        int idx = ntloadi(indices + i) - (S - 1);
        if (idx < 0) idx = 0;
        idxv[r] = idx;
        int b = idx >> shift; if (b > NBUCKET - 1) b = NBUCKET - 1;
        bckt[r] = b;

        unsigned long long mask = ~0ull;
        #pragma unroll
        for (int k = 0; k < 5; ++k) {
            unsigned long long bm = __ballot((b >> k) & 1);
            mask &= ((b >> k) & 1) ? bm : ~bm;
        }
        rnk[r] = __popcll(mask & ltmask);
        if (rnk[r] == 0) cnt[r][wave][b] = __popcll(mask);

        stream_compute(quat, tpos, bias, batchX, i, SF, last_off,
                       gx, gy, gz, half_dt2, cxv[r], cyv[r], czv[r]);
    }
    __syncthreads();

    if (tid < NBUCKET) {
        int b = tid, off = 0;
        #pragma unroll
        for (int r = 0; r < ROUNDS; ++r)
            #pragma unroll
            for (int w = 0; w < 4; ++w) {
                offarr[r][w][b] = off;
                off += cnt[r][w][b];
            }
        dirs[blockIdx.x * NBUCKET + b] = off;
        cnt[0][0][b] = off;
    }
    __syncthreads();
    if (tid == 0) {
        int s = 0;
        #pragma unroll
        for (int b = 0; b < NBUCKET; ++b) { bstart[b] = s; s += cnt[0][0][b]; }
    }
    __syncthreads();

    #pragma unroll
    for (int r = 0; r < ROUNDS; ++r) {
        int slot = bstart[bckt[r]] + offarr[r][wave][bckt[r]] + rnk[r];
        unsigned long long e =
            (unsigned long long)((unsigned)(idxv[r] - (bckt[r] << shift)) & 0xFFFFu)
          | ((unsigned long long)f2h(cxv[r]) << 16)
          | ((unsigned long long)f2h(cyv[r]) << 32)
          | ((unsigned long long)f2h(czv[r]) << 48);
        stage[slot] = e;
    }
    __syncthreads();

    #pragma unroll
    for (int r = 0; r < ROUNDS; ++r)
        pairs8[(size_t)base + r * NTHREADS + tid] = stage[r * NTHREADS + tid];
}

// ---------------- K2: XCD-sliced gather; optionally fused finish (cooperative) ----------------
template <bool FUSE>
__global__ __launch_bounds__(NTHREADS) void k2_gather(
    const float* __restrict__ pos_all,
    const float* __restrict__ vel_all,
    const unsigned long long* __restrict__ pairs8,
    const int*   __restrict__ dirs,
    int shift, int Nm1, int nseg, float inv_cnt,
    float* __restrict__ partials,
    float* __restrict__ out)
{
    const int r = blockIdx.x & 7;
    const int j = blockIdx.x >> 3;
    const int tid = threadIdx.x;

    __shared__ int dcnt[8][NBUCKET];
    __shared__ int segSrc[8];
    __shared__ int segCum[9];
    __shared__ float wsum[NTHREADS / 64];

    {
        int s = tid >> 5, bb = tid & (NBUCKET - 1);
        dcnt[s][bb] = dirs[(j * 8 + s) * NBUCKET + bb];
    }
    __syncthreads();

    float hsum = 0.f;

    for (int phase = 0; phase < NBUCKET / 8; ++phase) {
        const int b = r + 8 * phase;
        const int bbase = b << shift;

        if (tid < 8) {
            int s = tid, st = 0;
            for (int bb = 0; bb < b; ++bb) st += dcnt[s][bb];
            segSrc[s] = (j * 8 + s) * ELEMS_PER_BLOCK + st;
            segCum[s] = dcnt[s][b];
        }
        __syncthreads();
        if (tid == 0) {
            int c = 0;
            #pragma unroll
            for (int s = 0; s < 8; ++s) { int l = segCum[s]; segCum[s] = c; c += l; }
            segCum[8] = c;
        }
        __syncthreads();

        const int tot = segCum[8];
        for (int m = tid; m < tot; m += NTHREADS) {
            int s = 0;
            #pragma unroll
            for (int k = 1; k < 8; ++k) s += (m >= segCum[k]);
            unsigned long long e = ntload8(pairs8 + segSrc[s] + (m - segCum[s]));
            int idx = bbase + (int)(e & 0xFFFFull);

            float px, py, pz, vx, vy, vz;
            if (idx < Nm1) {
                fvec4u pv = *reinterpret_cast<const fvec4u*>(pos_all + (size_t)idx * 3);
                fvec4u vv = *reinterpret_cast<const fvec4u*>(vel_all + (size_t)idx * 3);
                px = pv.x; py = pv.y; pz = pv.z;
                vx = vv.x; vy = vv.y; vz = vv.z;
            } else {
                const float* pp = pos_all + (size_t)idx * 3;
                const float* vp = vel_all + (size_t)idx * 3;
                px = pp[0]; py = pp[1]; pz = pp[2];
                vx = vp[0]; vy = vp[1]; vz = vp[2];
            }

            hsum += huber3(px + vx * DT + h2f((unsigned short)(e >> 16)),
                           py + vy * DT + h2f((unsigned short)(e >> 32)),
                           pz + vz * DT + h2f((unsigned short)(e >> 48)));
        }
        __syncthreads();
    }

    for (int off = 32; off > 0; off >>= 1)
        hsum += __shfl_down(hsum, off);

    int lane = tid & 63, wid = tid >> 6;
    if (lane == 0) wsum[wid] = hsum;
    __syncthreads();
    if (tid == 0) {
        float s = 0.f;
        for (int w = 0; w < NTHREADS / 64; ++w) s += wsum[w];
        partials[blockIdx.x] = s;
    }

    if constexpr (FUSE) {
        __threadfence();
        cg::this_grid().sync();
        if (blockIdx.x == 0) {
            float s = 0.f;
            for (int i = tid; i < nseg; i += NTHREADS) s += partials[i];
            for (int off = 32; off > 0; off >>= 1)
                s += __shfl_down(s, off);
            __syncthreads();
            if (lane == 0) wsum[wid] = s;
            __syncthreads();
            if (tid == 0) {
                float tot = 0.f;
                for (int w = 0; w < NTHREADS / 64; ++w) tot += wsum[w];
                out[0] = tot * inv_cnt;
            }
        }
    }
}

// ---------------- Fallback: proven round-5 single-pass ----------------
__global__ __launch_bounds__(NTHREADS) void pos_loss_partial(
    const float* __restrict__ quat,
    const float* __restrict__ tpos,
    const float* __restrict__ bias,
    const float* __restrict__ batchX,
    const float* __restrict__ pos_all,
    const float* __restrict__ vel_all,
    const float* __restrict__ grav,
    const int*   __restrict__ indices,
    const int*   __restrict__ seq_len_p,
    int B, int SF,
    float* __restrict__ partials)
{
    const int S = *seq_len_p;
    const int F = SF / S;
    const int last_off = (S - 1) * F;
    const float gx = grav[0], gy = grav[1], gz = grav[2];
    const float half_dt2 = 0.5f * DT * DT;

    float hsum = 0.f;

    for (int i = blockIdx.x * blockDim.x + threadIdx.x; i < B;
         i += gridDim.x * blockDim.x) {
        int idx = ntloadi(indices + i) - (S - 1);
        if (idx < 0) idx = 0;
        const float* pp = pos_all + (size_t)idx * 3;
        const float* vp = vel_all + (size_t)idx * 3;
        float p0x = pp[0], p0y = pp[1], p0z = pp[2];
        float v0x = vp[0], v0y = vp[1], v0z = vp[2];

        fvec4 q = ntload4f(quat + (size_t)i * 4);
        const float* tp = tpos + (size_t)i * 3;
        float tpx = ntloadf(tp + 0), tpy = ntloadf(tp + 1), tpz = ntloadf(tp + 2);
        const float* bp = bias + (size_t)i * 3;
        float bx = ntloadf(bp + 0), by = ntloadf(bp + 1), bz = ntloadf(bp + 2);
        const float* xb = batchX + (size_t)i * SF + last_off;
        float ax = ntloadf(xb + 0) - bx;
        float ay = ntloadf(xb + 1) - by;
        float az = ntloadf(xb + 2) - bz;

        float t0 = -(q.y * ax + q.z * ay + q.w * az);
        float t1 =   q.x * ax + q.z * az - q.w * ay;
        float t2 =   q.x * ay - q.y * az + q.w * ax;
        float t3 =   q.x * az + q.y * ay - q.z * ax;
        float rx = -t0 * q.y + t1 * q.x - t2 * q.w + t3 * q.z;
        float ry = -t0 * q.z + t1 * q.w + t2 * q.x - t3 * q.y;
        float rz = -t0 * q.w - t1 * q.z + t2 * q.y + t3 * q.x;

        float px = p0x + v0x * DT + half_dt2 * (gx + rx);
        float py = p0y + v0y * DT + half_dt2 * (gy + ry);
        float pz = p0z + v0z * DT + half_dt2 * (gz + rz);

        hsum += huber3(px - tpx, py - tpy, pz - tpz);
    }

    for (int off = 32; off > 0; off >>= 1)
        hsum += __shfl_down(hsum, off);

    __shared__ float wsum[NTHREADS / 64];
    int lane = threadIdx.x & 63;
    int wid  = threadIdx.x >> 6;
    if (lane == 0) wsum[wid] = hsum;
    __syncthreads();
    if (threadIdx.x == 0) {
        float s = 0.f;
        for (int w = 0; w < NTHREADS / 64; ++w) s += wsum[w];
        partials[blockIdx.x] = s;
    }
}

__global__ __launch_bounds__(NTHREADS) void pos_loss_finish(
    const float* __restrict__ partials, int nb, float inv_cnt,
    float* __restrict__ out)
{
    float s = 0.f;
    for (int i = threadIdx.x; i < nb; i += NTHREADS) s += partials[i];
    for (int off = 32; off > 0; off >>= 1)
        s += __shfl_down(s, off);
    __shared__ float wsum[NTHREADS / 64];
    int lane = threadIdx.x & 63;
    int wid  = threadIdx.x >> 6;
    if (lane == 0) wsum[wid] = s;
    __syncthreads();
    if (threadIdx.x == 0) {
        float tot = 0.f;
        for (int w = 0; w < NTHREADS / 64; ++w) tot += wsum[w];
        out[0] = tot * inv_cnt;
    }
}

extern "C" void kernel_launch(void* const* d_in, const int* in_sizes, int n_in,
                              void* d_out, int out_size, void* d_ws, size_t ws_size,
                              hipStream_t stream) {
    const float* quat    = (const float*)d_in[0];
    const float* tpos    = (const float*)d_in[1];
    const float* bias    = (const float*)d_in[2];
    const float* batchX  = (const float*)d_in[3];
    const float* pos_all = (const float*)d_in[4];
    const float* vel_all = (const float*)d_in[5];
    const float* grav    = (const float*)d_in[6];
    const int*   indices = (const int*)d_in[7];
    const int*   seqlen  = (const int*)d_in[8];

    const int B  = in_sizes[0] / 4;
    const int SF = in_sizes[3] / B;
    const int N  = in_sizes[4] / 3;

    float inv_cnt = (float)(1.0 / (3.0 * (double)B));
    float* outp = (float*)d_out;

    const int nseg = B / ELEMS_PER_BLOCK;
    unsigned long long* pairs8 = (unsigned long long*)d_ws;
    int*   dirs     = (int*)((char*)d_ws + (size_t)B * 8);
    float* partials = (float*)((char*)d_ws + (size_t)B * 8 +
                               (size_t)nseg * NBUCKET * 4);
    const size_t need = (size_t)B * 8 + (size_t)nseg * NBUCKET * 4 +
                        (size_t)nseg * 4 + 256;

    int shift = 0;
    while (((long long)(N - 1) >> shift) >= NBUCKET) ++shift;

    const bool pipe_ok = (B % (ELEMS_PER_BLOCK * 8) == 0) && (ws_size >= need) &&
                         (N > NBUCKET) && (shift <= 16);

    if (pipe_ok) {
        k1_bin<<<nseg, NTHREADS, 0, stream>>>(
            quat, tpos, bias, batchX, grav, indices, seqlen,
            SF, shift, pairs8, dirs);

        // try cooperative K2 with fused finish
        bool coop_ok = true;
        int dev = 0;
        hipGetDevice(&dev);
        int coop_attr = 0;
        hipDeviceGetAttribute(&coop_attr, hipDeviceAttributeCooperativeLaunch, dev);
        int num_cu = 0;
        hipDeviceGetAttribute(&num_cu, hipDeviceAttributeMultiprocessorCount, dev);
        int max_blk = 0;
        hipOccupancyMaxActiveBlocksPerMultiprocessor(&max_blk, k2_gather<true>,
                                                     NTHREADS, 0);
        coop_ok = coop_attr && (max_blk * num_cu >= nseg);

        if (coop_ok) {
            int Nm1 = N - 1;
            void* args[] = {
                (void*)&pos_all, (void*)&vel_all, (void*)&pairs8, (void*)&dirs,
                (void*)&shift, (void*)&Nm1, (void*)&nseg, (void*)&inv_cnt,
                (void*)&partials, (void*)&outp
            };
            hipError_t err = hipLaunchCooperativeKernel(
                (const void*)k2_gather<true>, dim3(nseg), dim3(NTHREADS),
                args, 0, stream);
            if (err == hipSuccess) return;
        }

        k2_gather<false><<<nseg, NTHREADS, 0, stream>>>(
            pos_all, vel_all, pairs8, dirs, shift, N - 1, nseg, inv_cnt,
            partials, outp);
        pos_loss_finish<<<1, NTHREADS, 0, stream>>>(
            partials, nseg, inv_cnt, outp);
    } else {
        float* fpart = (float*)d_ws;
        pos_loss_partial<<<NBLOCKS, NTHREADS, 0, stream>>>(
            quat, tpos, bias, batchX, pos_all, vel_all, grav, indices, seqlen,
            B, SF, fpart);
        pos_loss_finish<<<1, NTHREADS, 0, stream>>>(
            fpart, NBLOCKS, inv_cnt, outp);
    }
}

// Round 17
// 57.477 us; speedup vs baseline: 4.0600x; 4.0600x over previous
//
#include <hip/hip_runtime.h>
#include <hip/hip_fp16.h>
#include <math.h>

#define DT 0.005f
#define NTHREADS 256
#define NBLOCKS 2048
#define NBUCKET 32
#define ELEMS_PER_BLOCK 1024
#define ROUNDS 4

typedef float    fvec4 __attribute__((ext_vector_type(4)));
typedef unsigned uvec4 __attribute__((ext_vector_type(4)));
// 4-byte-aligned 16B vector (gfx9 allows dword-aligned dwordx4; proven r15)
typedef float    fvec4u __attribute__((ext_vector_type(4), aligned(4)));

__device__ __forceinline__ fvec4 ntload4f(const float* p) {
    return __builtin_nontemporal_load(reinterpret_cast<const fvec4*>(p));
}
__device__ __forceinline__ float ntloadf(const float* p) {
    return __builtin_nontemporal_load(p);
}
__device__ __forceinline__ int ntloadi(const int* p) {
    return __builtin_nontemporal_load(p);
}
__device__ __forceinline__ unsigned long long ntload8(const unsigned long long* p) {
    return __builtin_nontemporal_load(p);
}

__device__ __forceinline__ unsigned short f2h(float f) {
    return __half_as_ushort(__float2half(f));
}
__device__ __forceinline__ float h2f(unsigned short u) {
    return __half2float(__ushort_as_half(u));
}

__device__ __forceinline__ void stream_compute(
    const float* __restrict__ quat, const float* __restrict__ tpos,
    const float* __restrict__ bias, const float* __restrict__ batchX,
    int i, int SF, int last_off,
    float gx, float gy, float gz, float half_dt2,
    float& cx, float& cy, float& cz)
{
    fvec4 q = ntload4f(quat + (size_t)i * 4);
    const float* tp = tpos + (size_t)i * 3;
    float tpx = ntloadf(tp + 0), tpy = ntloadf(tp + 1), tpz = ntloadf(tp + 2);
    const float* bp = bias + (size_t)i * 3;
    float bx = ntloadf(bp + 0), by = ntloadf(bp + 1), bz = ntloadf(bp + 2);
    // single 16B load (4B-aligned) covering the 12B accel sample
    const float* xb = batchX + (size_t)i * SF + last_off;
    fvec4u a = *reinterpret_cast<const fvec4u*>(xb);
    float ax = a.x - bx;
    float ay = a.y - by;
    float az = a.z - bz;

    float t0 = -(q.y * ax + q.z * ay + q.w * az);
    float t1 =   q.x * ax + q.z * az - q.w * ay;
    float t2 =   q.x * ay - q.y * az + q.w * ax;
    float t3 =   q.x * az + q.y * ay - q.z * ax;
    float rx = -t0 * q.y + t1 * q.x - t2 * q.w + t3 * q.z;
    float ry = -t0 * q.z + t1 * q.w + t2 * q.x - t3 * q.y;
    float rz = -t0 * q.w - t1 * q.z + t2 * q.y + t3 * q.x;

    cx = half_dt2 * (gx + rx) - tpx;
    cy = half_dt2 * (gy + ry) - tpy;
    cz = half_dt2 * (gz + rz) - tpz;
}

__device__ __forceinline__ float huber3(float dx, float dy, float dz) {
    float adx = fabsf(dx), ady = fabsf(dy), adz = fabsf(dz);
    float h = (adx < 1.f) ? 0.5f * dx * dx : adx - 0.5f;
    h += (ady < 1.f) ? 0.5f * dy * dy : ady - 0.5f;
    h += (adz < 1.f) ? 0.5f * dz * dz : adz - 0.5f;
    return h;
}

// ---------------- K1: stream + deterministic 32-bucket multisplit, 8B packed ----------------
__global__ __launch_bounds__(NTHREADS) void k1_bin(
    const float* __restrict__ quat,
    const float* __restrict__ tpos,
    const float* __restrict__ bias,
    const float* __restrict__ batchX,
    const float* __restrict__ grav,
    const int*   __restrict__ indices,
    const int*   __restrict__ seq_len_p,
    int SF, int shift,
    unsigned long long* __restrict__ pairs8,
    int*   __restrict__ dirs)
{
    const int S = *seq_len_p;
    const int F = SF / S;
    const int last_off = (S - 1) * F;
    const float gx = grav[0], gy = grav[1], gz = grav[2];
    const float half_dt2 = 0.5f * DT * DT;

    __shared__ int   cnt[ROUNDS][4][NBUCKET];
    __shared__ int   offarr[ROUNDS][4][NBUCKET];
    __shared__ int   bstart[NBUCKET];
    __shared__ unsigned long long stage[ELEMS_PER_BLOCK];

    const int tid  = threadIdx.x;
    const int wave = tid >> 6;
    const int lane = tid & 63;
    const unsigned long long ltmask = (1ull << lane) - 1ull;

    for (int k = tid; k < ROUNDS * 4 * NBUCKET; k += NTHREADS)
        ((int*)cnt)[k] = 0;
    __syncthreads();

    const int base = blockIdx.x * ELEMS_PER_BLOCK;

    int   idxv[ROUNDS], bckt[ROUNDS], rnk[ROUNDS];
    float cxv[ROUNDS], cyv[ROUNDS], czv[ROUNDS];

    #pragma unroll
    for (int r = 0; r < ROUNDS; ++r) {
        const int i = base + r * NTHREADS + tid;
        int idx = ntloadi(indices + i) - (S - 1);
        if (idx < 0) idx = 0;
        idxv[r] = idx;
        int b = idx >> shift; if (b > NBUCKET - 1) b = NBUCKET - 1;
        bckt[r] = b;

        unsigned long long mask = ~0ull;
        #pragma unroll
        for (int k = 0; k < 5; ++k) {
            unsigned long long bm = __ballot((b >> k) & 1);
            mask &= ((b >> k) & 1) ? bm : ~bm;
        }
        rnk[r] = __popcll(mask & ltmask);
        if (rnk[r] == 0) cnt[r][wave][b] = __popcll(mask);

        stream_compute(quat, tpos, bias, batchX, i, SF, last_off,
                       gx, gy, gz, half_dt2, cxv[r], cyv[r], czv[r]);
    }
    __syncthreads();

    if (tid < NBUCKET) {
        int b = tid, off = 0;
        #pragma unroll
        for (int r = 0; r < ROUNDS; ++r)
            #pragma unroll
            for (int w = 0; w < 4; ++w) {
                offarr[r][w][b] = off;
                off += cnt[r][w][b];
            }
        dirs[blockIdx.x * NBUCKET + b] = off;
        cnt[0][0][b] = off;
    }
    __syncthreads();
    if (tid == 0) {
        int s = 0;
        #pragma unroll
        for (int b = 0; b < NBUCKET; ++b) { bstart[b] = s; s += cnt[0][0][b]; }
    }
    __syncthreads();

    #pragma unroll
    for (int r = 0; r < ROUNDS; ++r) {
        int slot = bstart[bckt[r]] + offarr[r][wave][bckt[r]] + rnk[r];
        unsigned long long e =
            (unsigned long long)((unsigned)(idxv[r] - (bckt[r] << shift)) & 0xFFFFu)
          | ((unsigned long long)f2h(cxv[r]) << 16)
          | ((unsigned long long)f2h(cyv[r]) << 32)
          | ((unsigned long long)f2h(czv[r]) << 48);
        stage[slot] = e;
    }
    __syncthreads();

    #pragma unroll
    for (int r = 0; r < ROUNDS; ++r)
        pairs8[(size_t)base + r * NTHREADS + tid] = stage[r * NTHREADS + tid];
}

// ---------------- K2: XCD-sliced gather (plain launch, proven structure) ----------------
__global__ __launch_bounds__(NTHREADS) void k2_gather(
    const float* __restrict__ pos_all,
    const float* __restrict__ vel_all,
    const unsigned long long* __restrict__ pairs8,
    const int*   __restrict__ dirs,
    int shift, int Nm1,
    float* __restrict__ partials)
{
    const int r = blockIdx.x & 7;
    const int j = blockIdx.x >> 3;
    const int tid = threadIdx.x;

    __shared__ int dcnt[8][NBUCKET];
    __shared__ int segSrc[8];
    __shared__ int segCum[9];
    __shared__ float wsum[NTHREADS / 64];

    {
        int s = tid >> 5, bb = tid & (NBUCKET - 1);
        dcnt[s][bb] = dirs[(j * 8 + s) * NBUCKET + bb];
    }
    __syncthreads();

    float hsum = 0.f;

    for (int phase = 0; phase < NBUCKET / 8; ++phase) {
        const int b = r + 8 * phase;
        const int bbase = b << shift;

        if (tid < 8) {
            int s = tid, st = 0;
            for (int bb = 0; bb < b; ++bb) st += dcnt[s][bb];
            segSrc[s] = (j * 8 + s) * ELEMS_PER_BLOCK + st;
            segCum[s] = dcnt[s][b];
        }
        __syncthreads();
        if (tid == 0) {
            int c = 0;
            #pragma unroll
            for (int s = 0; s < 8; ++s) { int l = segCum[s]; segCum[s] = c; c += l; }
            segCum[8] = c;
        }
        __syncthreads();

        const int tot = segCum[8];
        for (int m = tid; m < tot; m += NTHREADS) {
            int s = 0;
            #pragma unroll
            for (int k = 1; k < 8; ++k) s += (m >= segCum[k]);
            unsigned long long e = ntload8(pairs8 + segSrc[s] + (m - segCum[s]));
            int idx = bbase + (int)(e & 0xFFFFull);

            float px, py, pz, vx, vy, vz;
            if (idx < Nm1) {
                fvec4u pv = *reinterpret_cast<const fvec4u*>(pos_all + (size_t)idx * 3);
                fvec4u vv = *reinterpret_cast<const fvec4u*>(vel_all + (size_t)idx * 3);
                px = pv.x; py = pv.y; pz = pv.z;
                vx = vv.x; vy = vv.y; vz = vv.z;
            } else {
                const float* pp = pos_all + (size_t)idx * 3;
                const float* vp = vel_all + (size_t)idx * 3;
                px = pp[0]; py = pp[1]; pz = pp[2];
                vx = vp[0]; vy = vp[1]; vz = vp[2];
            }

            hsum += huber3(px + vx * DT + h2f((unsigned short)(e >> 16)),
                           py + vy * DT + h2f((unsigned short)(e >> 32)),
                           pz + vz * DT + h2f((unsigned short)(e >> 48)));
        }
        __syncthreads();
    }

    for (int off = 32; off > 0; off >>= 1)
        hsum += __shfl_down(hsum, off);

    int lane = tid & 63, wid = tid >> 6;
    if (lane == 0) wsum[wid] = hsum;
    __syncthreads();
    if (tid == 0) {
        float s = 0.f;
        for (int w = 0; w < NTHREADS / 64; ++w) s += wsum[w];
        partials[blockIdx.x] = s;
    }
}

// ---------------- Fallback: proven round-5 single-pass ----------------
__global__ __launch_bounds__(NTHREADS) void pos_loss_partial(
    const float* __restrict__ quat,
    const float* __restrict__ tpos,
    const float* __restrict__ bias,
    const float* __restrict__ batchX,
    const float* __restrict__ pos_all,
    const float* __restrict__ vel_all,
    const float* __restrict__ grav,
    const int*   __restrict__ indices,
    const int*   __restrict__ seq_len_p,
    int B, int SF,
    float* __restrict__ partials)
{
    const int S = *seq_len_p;
    const int F = SF / S;
    const int last_off = (S - 1) * F;
    const float gx = grav[0], gy = grav[1], gz = grav[2];
    const float half_dt2 = 0.5f * DT * DT;

    float hsum = 0.f;

    for (int i = blockIdx.x * blockDim.x + threadIdx.x; i < B;
         i += gridDim.x * blockDim.x) {
        int idx = ntloadi(indices + i) - (S - 1);
        if (idx < 0) idx = 0;
        const float* pp = pos_all + (size_t)idx * 3;
        const float* vp = vel_all + (size_t)idx * 3;
        float p0x = pp[0], p0y = pp[1], p0z = pp[2];
        float v0x = vp[0], v0y = vp[1], v0z = vp[2];

        fvec4 q = ntload4f(quat + (size_t)i * 4);
        const float* tp = tpos + (size_t)i * 3;
        float tpx = ntloadf(tp + 0), tpy = ntloadf(tp + 1), tpz = ntloadf(tp + 2);
        const float* bp = bias + (size_t)i * 3;
        float bx = ntloadf(bp + 0), by = ntloadf(bp + 1), bz = ntloadf(bp + 2);
        const float* xb = batchX + (size_t)i * SF + last_off;
        float ax = ntloadf(xb + 0) - bx;
        float ay = ntloadf(xb + 1) - by;
        float az = ntloadf(xb + 2) - bz;

        float t0 = -(q.y * ax + q.z * ay + q.w * az);
        float t1 =   q.x * ax + q.z * az - q.w * ay;
        float t2 =   q.x * ay - q.y * az + q.w * ax;
        float t3 =   q.x * az + q.y * ay - q.z * ax;
        float rx = -t0 * q.y + t1 * q.x - t2 * q.w + t3 * q.z;
        float ry = -t0 * q.z + t1 * q.w + t2 * q.x - t3 * q.y;
        float rz = -t0 * q.w - t1 * q.z + t2 * q.y + t3 * q.x;

        float px = p0x + v0x * DT + half_dt2 * (gx + rx);
        float py = p0y + v0y * DT + half_dt2 * (gy + ry);
        float pz = p0z + v0z * DT + half_dt2 * (gz + rz);

        hsum += huber3(px - tpx, py - tpy, pz - tpz);
    }

    for (int off = 32; off > 0; off >>= 1)
        hsum += __shfl_down(hsum, off);

    __shared__ float wsum[NTHREADS / 64];
    int lane = threadIdx.x & 63;
    int wid  = threadIdx.x >> 6;
    if (lane == 0) wsum[wid] = hsum;
    __syncthreads();
    if (threadIdx.x == 0) {
        float s = 0.f;
        for (int w = 0; w < NTHREADS / 64; ++w) s += wsum[w];
        partials[blockIdx.x] = s;
    }
}

__global__ __launch_bounds__(NTHREADS) void pos_loss_finish(
    const float* __restrict__ partials, int nb, float inv_cnt,
    float* __restrict__ out)
{
    float s = 0.f;
    for (int i = threadIdx.x; i < nb; i += NTHREADS) s += partials[i];
    for (int off = 32; off > 0; off >>= 1)
        s += __shfl_down(s, off);
    __shared__ float wsum[NTHREADS / 64];
    int lane = threadIdx.x & 63;
    int wid  = threadIdx.x >> 6;
    if (lane == 0) wsum[wid] = s;
    __syncthreads();
    if (threadIdx.x == 0) {
        float tot = 0.f;
        for (int w = 0; w < NTHREADS / 64; ++w) tot += wsum[w];
        out[0] = tot * inv_cnt;
    }
}

extern "C" void kernel_launch(void* const* d_in, const int* in_sizes, int n_in,
                              void* d_out, int out_size, void* d_ws, size_t ws_size,
                              hipStream_t stream) {
    const float* quat    = (const float*)d_in[0];
    const float* tpos    = (const float*)d_in[1];
    const float* bias    = (const float*)d_in[2];
    const float* batchX  = (const float*)d_in[3];
    const float* pos_all = (const float*)d_in[4];
    const float* vel_all = (const float*)d_in[5];
    const float* grav    = (const float*)d_in[6];
    const int*   indices = (const int*)d_in[7];
    const int*   seqlen  = (const int*)d_in[8];

    const int B  = in_sizes[0] / 4;
    const int SF = in_sizes[3] / B;
    const int N  = in_sizes[4] / 3;

    float inv_cnt = (float)(1.0 / (3.0 * (double)B));
    float* outp = (float*)d_out;

    const int nseg = B / ELEMS_PER_BLOCK;
    unsigned long long* pairs8 = (unsigned long long*)d_ws;
    int*   dirs     = (int*)((char*)d_ws + (size_t)B * 8);
    float* partials = (float*)((char*)d_ws + (size_t)B * 8 +
                               (size_t)nseg * NBUCKET * 4);
    const size_t need = (size_t)B * 8 + (size_t)nseg * NBUCKET * 4 +
                        (size_t)nseg * 4 + 256;

    int shift = 0;
    while (((long long)(N - 1) >> shift) >= NBUCKET) ++shift;

    const bool pipe_ok = (B % (ELEMS_PER_BLOCK * 8) == 0) && (ws_size >= need) &&
                         (N > NBUCKET) && (shift <= 16);

    if (pipe_ok) {
        k1_bin<<<nseg, NTHREADS, 0, stream>>>(
            quat, tpos, bias, batchX, grav, indices, seqlen,
            SF, shift, pairs8, dirs);
        k2_gather<<<nseg, NTHREADS, 0, stream>>>(
            pos_all, vel_all, pairs8, dirs, shift, N - 1, partials);
        pos_loss_finish<<<1, NTHREADS, 0, stream>>>(
            partials, nseg, inv_cnt, outp);
    } else {
        float* fpart = (float*)d_ws;
        pos_loss_partial<<<NBLOCKS, NTHREADS, 0, stream>>>(
            quat, tpos, bias, batchX, pos_all, vel_all, grav, indices, seqlen,
            B, SF, fpart);
        pos_loss_finish<<<1, NTHREADS, 0, stream>>>(
            fpart, NBLOCKS, inv_cnt, outp);
    }
}